// Round 4
// baseline (162.852 us; speedup 1.0000x reference)
//
#include <hip/hip_runtime.h>

// Problem: B=8, S=2048, H=1024, D=64. fp32 in, fp32 out.
// out = softmax_causal(q k^T) / sqrt(H) @ v   (softmax FIRST, then /32)

typedef float     f32x4 __attribute__((ext_vector_type(4)));
typedef _Float16  f16x8 __attribute__((ext_vector_type(8)));
typedef _Float16  f16x4 __attribute__((ext_vector_type(4)));

#define L2E 1.44269504088896340736f

// ---------------------------------------------------------------------------
// Kernel 1: pack W{q,k,v} into MFMA B-fragment order (f16) via LDS transpose.
// Frag (kstep*12+nt)*64+lane holds 8 f16: W[n=nt*16+(lane&15)][k=kstep*32+(lane>>4)*8+j]
__global__ __launch_bounds__(256) void wt_prep(const float* __restrict__ Wq,
                                               const float* __restrict__ Wk,
                                               const float* __restrict__ Wv,
                                               _Float16* __restrict__ WtF) {
  const int w  = blockIdx.x >> 4;              // which W
  const int kt = blockIdx.x & 15;              // k-tile of 64
  const float* src = (w == 0) ? Wq : (w == 1 ? Wk : Wv);
  __shared__ _Float16 ls[64][72];
  const int t = threadIdx.x;
  {
    int rr = t >> 4;
    int c4 = (t & 15) * 4;
    #pragma unroll
    for (int ri = 0; ri < 4; ++ri) {
      int k = rr + ri * 16;
      f32x4 f = *(const f32x4*)&src[(size_t)(kt * 64 + k) * 64 + c4];
      #pragma unroll
      for (int j = 0; j < 4; ++j) ls[k][c4 + j] = (_Float16)f[j];
    }
  }
  __syncthreads();
  const int lane = t & 63, l16 = lane & 15, quad = lane >> 4;
  #pragma unroll
  for (int h = 0; h < 2; ++h) {
    int fid     = h * 4 + (t >> 6);
    int kstep_l = fid >> 2;
    int ntl     = fid & 3;
    int nt      = w * 4 + ntl;
    int kstep   = kt * 2 + kstep_l;
    f16x8 o;
    #pragma unroll
    for (int j = 0; j < 8; ++j) o[j] = ls[kstep_l * 32 + quad * 8 + j][ntl * 16 + l16];
    *(f16x8*)&WtF[((size_t)(kstep * 12 + nt) * 64 + lane) * 8] = o;
  }
}

// ---------------------------------------------------------------------------
// Kernel 2: QKV projection. Grid 512 (M-tile=32), 768 threads (12 waves =
// 2 mhalf x 6 ngrp of 2 n-tiles) -> 2 blocks/CU = 24 waves/CU to hide the L2
// B-frag latency. Whole 32x1024 x-tile staged once (XOR-swizzled 64KB LDS,
// single barrier); each wave streams 64 coalesced B-frag loads + 64 MFMAs.
__global__ __launch_bounds__(768) void qkv_gemm(const float* __restrict__ x,
                                                const _Float16* __restrict__ WtF,
                                                const float* __restrict__ bq,
                                                const float* __restrict__ bk,
                                                const float* __restrict__ bv,
                                                _Float16* __restrict__ qo,
                                                _Float16* __restrict__ ko,
                                                _Float16* __restrict__ vt) {
  __shared__ _Float16 xs[32 * 1024];           // 64 KB
  const int tid  = threadIdx.x;
  const int wave = tid >> 6, lane = tid & 63;
  const int l16  = lane & 15, quad = lane >> 4;
  const int mhalf = wave / 6;                  // 0..1
  const int ngrp  = wave - mhalf * 6;          // 0..5, owns n-tiles ngrp*2, +1
  const int m0    = blockIdx.x * 32;

  if (tid < 512) {                             // waves 0..7 stage x (fp32->f16)
    int row   = tid >> 4;                      // 0..31
    int cbase = (tid & 15) * 4;
    const float* xrow = x + (size_t)(m0 + row) * 1024;
    int key = row & 7;
    #pragma unroll
    for (int j = 0; j < 16; ++j) {
      int col = cbase + j * 64;
      f32x4 f = *(const f32x4*)&xrow[col];
      f16x4 hh;
      #pragma unroll
      for (int e = 0; e < 4; ++e) hh[e] = (_Float16)f[e];
      int g   = col >> 3;                      // granule 0..127
      int sub = col & 7;
      *(f16x4*)&xs[(size_t)row * 1024 + (size_t)((g ^ key) << 3) + sub] = hh;
    }
  }
  __syncthreads();

  f32x4 acc0 = (f32x4){0.f,0.f,0.f,0.f};
  f32x4 acc1 = (f32x4){0.f,0.f,0.f,0.f};
  const int arow = mhalf * 16 + l16;
  const _Float16* abase = xs + (size_t)arow * 1024;
  const int akey = arow & 7;
  const _Float16* wbase = WtF + ((size_t)(ngrp * 2) * 64 + lane) * 8;

  #pragma unroll 4
  for (int kstep = 0; kstep < 32; ++kstep) {
    f16x8 a = *(const f16x8*)(abase + (((kstep * 4 + quad) ^ akey) << 3));
    const _Float16* wk = wbase + (size_t)kstep * (12 * 64 * 8);
    f16x8 b0 = *(const f16x8*)(wk);
    f16x8 b1 = *(const f16x8*)(wk + 512);
    acc0 = __builtin_amdgcn_mfma_f32_16x16x32_f16(a, b0, acc0, 0, 0, 0);
    acc1 = __builtin_amdgcn_mfma_f32_16x16x32_f16(a, b1, acc1, 0, 0, 0);
  }

  f32x4 accs[2] = {acc0, acc1};
  #pragma unroll
  for (int i = 0; i < 2; ++i) {
    int nt  = ngrp * 2 + i;
    int col = nt * 16 + l16;
    float bias = (nt < 4) ? bq[col] : (nt < 8) ? bk[col - 64] : bv[col - 128];
    #pragma unroll
    for (int r = 0; r < 4; ++r) {
      int m = m0 + mhalf * 16 + quad * 4 + r;  // global row = b*2048+s
      _Float16 hv = (_Float16)(accs[i][r] + bias);
      if (nt < 4)      qo[(size_t)m * 64 + col] = hv;
      else if (nt < 8) ko[(size_t)m * 64 + (col - 64)] = hv;
      else {                                   // v stored transposed: vt[b][d][s]
        int b = m >> 11, s = m & 2047;
        vt[((size_t)b * 64 + (col - 128)) * 2048 + s] = hv;
      }
    }
  }
}

// ---------------------------------------------------------------------------
// Kernel 3: causal attention, K-major scores, one 64-KV chunk per wave,
// work-proportional cross-block split-KV. Block (bid 0..575, batch): q-tile qt
// has (qt>>4)+1 splits of 256 kv; 4 waves take 64 kv each -> NO online
// rescaling (single max/sum). Softmax reduction: 15 in-lane ops + 2 shuffles
// (scores are kv-major: C col = q, row = kv). In-block LDS merge -> f16
// partial (o,m,l); attn_merge combines splits.
__global__ __launch_bounds__(256) void attn(const _Float16* __restrict__ q,
                                            const _Float16* __restrict__ k,
                                            const _Float16* __restrict__ vt,
                                            _Float16* __restrict__ po,
                                            float* __restrict__ pm,
                                            float* __restrict__ pl) {
  const int bid = 575 - blockIdx.x;            // heavy-first
  const int b   = blockIdx.y;
  int g = 0;                                   // group: qt in [16g,16g+16), g+1 splits
  #pragma unroll
  for (int gg = 0; gg < 7; ++gg) if (bid >= 8 * (gg + 1) * (gg + 2)) g = gg + 1;
  const int r   = bid - 8 * g * (g + 1);
  const int qi  = r / (g + 1);                 // 0..15 (uniform, once)
  const int qt  = 16 * g + qi;
  const int s   = r - qi * (g + 1);            // split 0..g
  const int q0  = qt * 16, kvend = q0 + 16;

  const int tid  = threadIdx.x;
  const int wave = tid >> 6, lane = tid & 63;
  const int l16  = lane & 15, quad = lane >> 4;
  const int kv0  = s * 256 + wave * 64;

  __shared__ float ow[4][64][17];              // per-wave O^T[d][q]; [wave] also aliases P
  __shared__ float mw[4][16], lw[4][16];
  _Float16* Plw = (_Float16*)&ow[wave][0][0];  // per-wave P buffer [16 q][72 kv]

  float m = -1e30f, l = 0.f;
  f32x4 o[4];
  #pragma unroll
  for (int i = 0; i < 4; ++i) o[i] = (f32x4){0.f, 0.f, 0.f, 0.f};

  if (kv0 < kvend) {                           // wave-uniform
    const _Float16* qb = q  + (size_t)b * 2048 * 64;
    const _Float16* kb = k  + (size_t)b * 2048 * 64;
    const _Float16* vb = vt + (size_t)b * 64 * 2048;
    // Q as B-operand: B[k=d=quad*8+j][n=q=l16] == Q[q0+l16][quad*8+j]
    f16x8 qf0 = *(const f16x8*)&qb[(q0 + l16) * 64 + quad * 8];
    f16x8 qf1 = *(const f16x8*)&qb[(q0 + l16) * 64 + 32 + quad * 8];

    f32x4 sc[4];
    #pragma unroll
    for (int t = 0; t < 4; ++t) {
      int kvc = kv0 + t * 16;
      if (kvc < kvend) {                       // K as A: A[m=kv=l16][k=d]
        f16x8 kf0 = *(const f16x8*)&kb[(kvc + l16) * 64 + quad * 8];
        f16x8 kf1 = *(const f16x8*)&kb[(kvc + l16) * 64 + 32 + quad * 8];
        f32x4 c = (f32x4){0.f, 0.f, 0.f, 0.f};
        c = __builtin_amdgcn_mfma_f32_16x16x32_f16(kf0, qf0, c, 0, 0, 0);
        c = __builtin_amdgcn_mfma_f32_16x16x32_f16(kf1, qf1, c, 0, 0, 0);
        sc[t] = c;
      } else sc[t] = (f32x4){-1e30f, -1e30f, -1e30f, -1e30f};
    }
    // causal mask: row = kv = kvc+quad*4+rr, col = q = q0+l16
    if (kv0 + 63 > q0) {
      #pragma unroll
      for (int t = 0; t < 4; ++t) {
        #pragma unroll
        for (int rr = 0; rr < 4; ++rr) {
          int skv = kv0 + t * 16 + quad * 4 + rr;
          if (skv > q0 + l16) sc[t][rr] = -1e30f;
        }
      }
    }
    // max over kv for this q: 15 in-lane + 2 shuffles (kv0 <= q0 guarantees >=1 valid)
    float mx = sc[0][0];
    #pragma unroll
    for (int t = 0; t < 4; ++t)
      #pragma unroll
      for (int rr = 0; rr < 4; ++rr) mx = fmaxf(mx, sc[t][rr]);
    mx = fmaxf(mx, __shfl_xor(mx, 16, 64));
    mx = fmaxf(mx, __shfl_xor(mx, 32, 64));
    m = mx;
    float sum = 0.f;
    #pragma unroll
    for (int t = 0; t < 4; ++t)
      #pragma unroll
      for (int rr = 0; rr < 4; ++rr) {
        float e = exp2f((sc[t][rr] - m) * L2E);  // masked -> 0
        sc[t][rr] = e;
        sum += e;
      }
    sum += __shfl_xor(sum, 16, 64);
    sum += __shfl_xor(sum, 32, 64);
    l = sum;
    // P -> LDS [q][kv], then read PV B-frags: B[k=kv=quad*8+j][n=q=l16]
    #pragma unroll
    for (int t = 0; t < 4; ++t)
      #pragma unroll
      for (int rr = 0; rr < 4; ++rr)
        Plw[l16 * 72 + t * 16 + quad * 4 + rr] = (_Float16)sc[t][rr];
    asm volatile("s_waitcnt lgkmcnt(0)" ::: "memory");
    f16x8 p0 = *(const f16x8*)&Plw[l16 * 72 + quad * 8];
    f16x8 p1 = *(const f16x8*)&Plw[l16 * 72 + 32 + quad * 8];
    // O^T[d][q] += Vt[d][kv] * P[kv][q]; Vt as A: A[m=d=l16][k=kv=quad*8+j]
    #pragma unroll
    for (int dt = 0; dt < 4; ++dt) {
      f16x8 v0 = *(const f16x8*)&vb[(size_t)(dt * 16 + l16) * 2048 + kv0 + quad * 8];
      f16x8 v1 = *(const f16x8*)&vb[(size_t)(dt * 16 + l16) * 2048 + kv0 + 32 + quad * 8];
      o[dt] = __builtin_amdgcn_mfma_f32_16x16x32_f16(v0, p0, o[dt], 0, 0, 0);
      o[dt] = __builtin_amdgcn_mfma_f32_16x16x32_f16(v1, p1, o[dt], 0, 0, 0);
    }
  }

  __syncthreads();                             // all Plw reads done before ow overwrite
  #pragma unroll
  for (int dt = 0; dt < 4; ++dt)
    #pragma unroll
    for (int rr = 0; rr < 4; ++rr)
      ow[wave][dt * 16 + quad * 4 + rr][l16] = o[dt][rr];
  if (quad == 0) { mw[wave][l16] = m; lw[wave][l16] = l; }
  __syncthreads();

  // merge 4 waves -> block partial (f16 o, f32 m,l)
  {
    int qrow = tid >> 4, d4 = (tid & 15) * 4;
    float m0v = mw[0][qrow], m1v = mw[1][qrow], m2v = mw[2][qrow], m3v = mw[3][qrow];
    float M = fmaxf(fmaxf(m0v, m1v), fmaxf(m2v, m3v));
    float w0 = exp2f((m0v - M) * L2E), w1 = exp2f((m1v - M) * L2E);
    float w2 = exp2f((m2v - M) * L2E), w3 = exp2f((m3v - M) * L2E);
    float L = w0 * lw[0][qrow] + w1 * lw[1][qrow] + w2 * lw[2][qrow] + w3 * lw[3][qrow];
    size_t pid = (size_t)b * 576 + bid;
    f16x4 oh;
    #pragma unroll
    for (int j = 0; j < 4; ++j)
      oh[j] = (_Float16)(w0 * ow[0][d4 + j][qrow] + w1 * ow[1][d4 + j][qrow]
                       + w2 * ow[2][d4 + j][qrow] + w3 * ow[3][d4 + j][qrow]);
    *(f16x4*)&po[pid * 1024 + (size_t)qrow * 64 + d4] = oh;
    if ((tid & 15) == 0) { pm[pid * 16 + qrow] = M; pl[pid * 16 + qrow] = L; }
  }
}

// ---------------------------------------------------------------------------
// Kernel 4: merge the (qt>>4)+1 splits of each q-tile, normalize, write out.
__global__ __launch_bounds__(256) void attn_merge(const _Float16* __restrict__ po,
                                                  const float* __restrict__ pm,
                                                  const float* __restrict__ pl,
                                                  float* __restrict__ out) {
  const int qt = blockIdx.x, b = blockIdx.y;
  const int g = qt >> 4, S = g + 1;
  const size_t base = (size_t)b * 576 + (size_t)(g + 1) * (8 * g + (qt & 15));
  const int t = threadIdx.x, qrow = t >> 4, d4 = (t & 15) * 4;

  float M = -1e30f;
  for (int s = 0; s < S; ++s) M = fmaxf(M, pm[(base + s) * 16 + qrow]);
  float L = 0.f;
  float O0 = 0.f, O1 = 0.f, O2 = 0.f, O3 = 0.f;
  for (int s = 0; s < S; ++s) {
    float w = exp2f((pm[(base + s) * 16 + qrow] - M) * L2E);
    L += w * pl[(base + s) * 16 + qrow];
    f16x4 ov = *(const f16x4*)&po[(base + s) * 1024 + (size_t)qrow * 64 + d4];
    O0 += w * (float)ov[0]; O1 += w * (float)ov[1];
    O2 += w * (float)ov[2]; O3 += w * (float)ov[3];
  }
  float inv = 1.0f / (L * 32.0f);              // sqrt(H)=32 applied AFTER softmax
  f32x4 res = (f32x4){O0 * inv, O1 * inv, O2 * inv, O3 * inv};
  *(f32x4*)&out[((size_t)b * 2048 + qt * 16 + qrow) * 64 + d4] = res;
}

// ---------------------------------------------------------------------------
extern "C" void kernel_launch(void* const* d_in, const int* in_sizes, int n_in,
                              void* d_out, int out_size, void* d_ws, size_t ws_size,
                              hipStream_t stream) {
  const float* x  = (const float*)d_in[0];
  const float* Wq = (const float*)d_in[1];
  const float* bq = (const float*)d_in[2];
  const float* Wk = (const float*)d_in[3];
  const float* bk = (const float*)d_in[4];
  const float* Wv = (const float*)d_in[5];
  const float* bv = (const float*)d_in[6];
  float* out = (float*)d_out;

  // ws: WtF 384KB | q 2MB | k 2MB | vt 2MB | po 9.4MB f16 | pm/pl 288KB f32
  _Float16* WtF = (_Float16*)d_ws;
  _Float16* qo  = WtF + 192 * 1024;
  _Float16* ko  = qo + 16384 * 64;
  _Float16* vt  = ko + 16384 * 64;
  _Float16* po  = vt + 8 * 64 * 2048;
  float*    pm  = (float*)(po + (size_t)4608 * 1024);
  float*    pl  = pm + 4608 * 16;

  hipLaunchKernelGGL(wt_prep,    dim3(48),       dim3(256), 0, stream, Wq, Wk, Wv, WtF);
  hipLaunchKernelGGL(qkv_gemm,   dim3(512),      dim3(768), 0, stream, x, WtF, bq, bk, bv, qo, ko, vt);
  hipLaunchKernelGGL(attn,       dim3(576, 8),   dim3(256), 0, stream, qo, ko, vt, po, pm, pl);
  hipLaunchKernelGGL(attn_merge, dim3(128, 8),   dim3(256), 0, stream, po, pm, pl, out);
}